// Round 6
// baseline (3294.802 us; speedup 1.0000x reference)
//
#include <hip/hip_runtime.h>

#define N_NODES 100000
#define N_EDGES 1600000
#define D_FEAT  64
#define K_STEPS 8
#define NB_SCAN ((N_NODES + 255) / 256)   // 391 scan blocks
#define TILES   16
#define TILE_W  6250                       // 16 * 6250 = 100000 exactly
#define NV      25                         // nodes owned per wave
#define PROP_BLOCKS 1024                   // 4096 waves * 25 = 102400 >= N

typedef unsigned long long u64;

__device__ __forceinline__ int src_tile(int s) { return (int)((unsigned)s / (unsigned)TILE_W); }

__global__ void k_zero(int* __restrict__ p, int n) {
    int i = blockIdx.x * blockDim.x + threadIdx.x;
    if (i < n) p[i] = 0;
}

// Histogram into (src-tile, dst) buckets; atomic return = rank within bucket.
__global__ void k_hist(const int* __restrict__ dst, const int* __restrict__ src,
                       int* __restrict__ cnt16, int* __restrict__ rank, int n) {
    int i = blockIdx.x * blockDim.x + threadIdx.x;
    if (i < n) {
        int t = src_tile(src[i]);
        rank[i] = atomicAdd(&cnt16[t * N_NODES + dst[i]], 1);
    }
}

// Per-node: exclusive prefix over the 16 tile buckets -> tilePre, total -> counts.
__global__ void k_tilescan(const int* __restrict__ cnt16, int* __restrict__ tilePre,
                           int* __restrict__ counts, int n) {
    int v = blockIdx.x * blockDim.x + threadIdx.x;
    if (v >= n) return;
    int run = 0;
    #pragma unroll
    for (int t = 0; t < TILES; ++t) {
        int c = cnt16[t * N_NODES + v];
        tilePre[t * N_NODES + v] = run;
        run += c;
    }
    counts[v] = run;
}

// Phase 1: per-block sum of 256 counts
__global__ void k_bsum(const int* __restrict__ counts, int* __restrict__ blockSums, int n) {
    __shared__ int ws[4];
    int t = threadIdx.x;
    int i = blockIdx.x * 256 + t;
    int c = (i < n) ? counts[i] : 0;
    for (int off = 32; off; off >>= 1) c += __shfl_down(c, off);
    if ((t & 63) == 0) ws[t >> 6] = c;
    __syncthreads();
    if (t == 0) blockSums[blockIdx.x] = ws[0] + ws[1] + ws[2] + ws[3];
}

// Phase 2: single block scans the 391 block sums -> exclusive blockPrefix
__global__ void k_sscan(const int* __restrict__ blockSums, int* __restrict__ blockPrefix,
                        int* __restrict__ offsets, int nb, int n) {
    __shared__ int sh[512];
    int t = threadIdx.x;
    int v = (t < nb) ? blockSums[t] : 0;
    sh[t] = v;
    __syncthreads();
    for (int off = 1; off < 512; off <<= 1) {
        int u = (t >= off) ? sh[t - off] : 0;
        __syncthreads();
        sh[t] += u;
        __syncthreads();
    }
    if (t < nb) blockPrefix[t] = sh[t] - v;   // exclusive
    if (t == 511) offsets[n] = sh[511];        // total == N_EDGES
}

// Phase 3: per-block exclusive scan of counts + block prefix -> offsets
__global__ void k_bscan(const int* __restrict__ counts, const int* __restrict__ blockPrefix,
                        int* __restrict__ offsets, int n) {
    __shared__ int sh[256];
    int t = threadIdx.x;
    int i = blockIdx.x * 256 + t;
    int c = (i < n) ? counts[i] : 0;
    sh[t] = c;
    __syncthreads();
    for (int off = 1; off < 256; off <<= 1) {
        int u = (t >= off) ? sh[t - off] : 0;
        __syncthreads();
        sh[t] += u;
        __syncthreads();
    }
    int excl = sh[t] - c + blockPrefix[blockIdx.x];
    if (i < n) offsets[i] = excl;
}

// Atomic-free scatter: pos = offsets[dst] + tilePre[tile][dst] + rank.
__global__ void k_scatter(const int* __restrict__ src, const int* __restrict__ dst,
                          const float* __restrict__ w, const int* __restrict__ offsets,
                          const int* __restrict__ tilePre, const int* __restrict__ rank,
                          u64* __restrict__ csr, int n) {
    int i = blockIdx.x * blockDim.x + threadIdx.x;
    if (i < n) {
        int s = src[i];
        int d = dst[i];
        int t = src_tile(s);
        int pos = offsets[d] + tilePre[t * N_NODES + d] + rank[i];
        u64 p = ((u64)__float_as_uint(w[i]) << 32) | (unsigned)s;
        __builtin_nontemporal_store(p, &csr[pos]);
    }
}

// Persistent tile-phased propagation. 4096 waves, each owning NV=25 nodes,
// all resident (launch_bounds caps VGPR). lane = feature: each edge's 256B
// row load is one fully-coalesced dword per lane. Waves sweep src-tiles
// 0..15 in (approximate) lockstep, so concurrent gathers hit a ~1.6MB
// h-slab that fits each XCD's private L2. Tile of an edge is derived from
// the packed src field; lists are tile-sorted by the build.
__global__ __launch_bounds__(256, 4)
void k_prop_tiled(const float* __restrict__ hin, float* __restrict__ hout,
                  const int* __restrict__ offsets, const u64* __restrict__ csr, int n) {
    int wid  = (blockIdx.x * blockDim.x + threadIdx.x) >> 6;
    int lane = threadIdx.x & 63;
    int base = wid * NV;

    int   cur[NV];
    int   end[NV];
    float acc[NV];
    #pragma unroll
    for (int i = 0; i < NV; ++i) {
        int v = base + i;
        bool ok = v < n;
        cur[i] = ok ? offsets[v] : 0;
        end[i] = ok ? offsets[v + 1] : 0;
        acc[i] = 0.f;
    }

    for (int t = 0; t < TILES; ++t) {
        int lim = (t + 1) * TILE_W;
        #pragma unroll
        for (int i = 0; i < NV; ++i) {
            while (cur[i] < end[i]) {
                u64 p = csr[cur[i]];                 // wave-uniform 8B load
                int s = (int)(p & 0xffffffffu);
                if (s >= lim) break;                  // next tile's bucket
                float w = __uint_as_float((unsigned)(p >> 32));
                acc[i] = fmaf(w, hin[((size_t)s << 6) | lane], acc[i]);
                cur[i]++;
            }
        }
        __syncthreads();   // keep the block's 4 waves phase-aligned
    }

    #pragma unroll
    for (int i = 0; i < NV; ++i) {
        int v = base + i;
        if (v < n)
            __builtin_nontemporal_store(acc[i], &hout[((size_t)v << 6) | lane]);
    }
}

extern "C" void kernel_launch(void* const* d_in, const int* in_sizes, int n_in,
                              void* d_out, int out_size, void* d_ws, size_t ws_size,
                              hipStream_t stream) {
    const float* x   = (const float*)d_in[0];
    const float* ew  = (const float*)d_in[1];
    const int*   src = (const int*)d_in[2];
    const int*   dst = (const int*)d_in[3];
    float* out = (float*)d_out;

    // Workspace (~39.7 MB). rank/cnt16/tilePre alias hA: all are dead before
    // the first prop writes hA (3 x 1.6M ints = 19.2MB <= hA's 25.6MB).
    float* hA         = (float*)d_ws;                            // N*D floats
    int*   rank       = (int*)d_ws;                              // E ints
    int*   cnt16      = rank + N_EDGES;                          // TILES*N ints
    int*   tilePre    = cnt16 + TILES * N_NODES;                 // TILES*N ints
    u64*   csr        = (u64*)(hA + (size_t)N_NODES * D_FEAT);   // E x 8B packed (src,w)
    int*   offsets    = (int*)(csr + N_EDGES);                   // N+1 ints
    int*   counts     = offsets + (N_NODES + 1);                 // N ints
    int*   blockSums  = counts + N_NODES;                        // NB_SCAN ints
    int*   blockPref  = blockSums + NB_SCAN;                     // NB_SCAN ints

    k_zero<<<(TILES * N_NODES + 255) / 256, 256, 0, stream>>>(cnt16, TILES * N_NODES);
    k_hist<<<(N_EDGES + 255) / 256, 256, 0, stream>>>(dst, src, cnt16, rank, N_EDGES);
    k_tilescan<<<(N_NODES + 255) / 256, 256, 0, stream>>>(cnt16, tilePre, counts, N_NODES);
    k_bsum<<<NB_SCAN, 256, 0, stream>>>(counts, blockSums, N_NODES);
    k_sscan<<<1, 512, 0, stream>>>(blockSums, blockPref, offsets, NB_SCAN, N_NODES);
    k_bscan<<<NB_SCAN, 256, 0, stream>>>(counts, blockPref, offsets, N_NODES);
    k_scatter<<<(N_EDGES + 255) / 256, 256, 0, stream>>>(src, dst, ew, offsets, tilePre,
                                                         rank, csr, N_EDGES);

    const float* in = x;
    for (int k = 0; k < K_STEPS; ++k) {
        float* o = ((k & 1) == 0) ? hA : out;   // k=7 (last) writes d_out
        k_prop_tiled<<<PROP_BLOCKS, 256, 0, stream>>>(in, o, offsets, csr, N_NODES);
        in = o;
    }
}

// Round 7
// 2396.455 us; speedup vs baseline: 1.3749x; 1.3749x over previous
//
#include <hip/hip_runtime.h>

#define N_NODES 100000
#define N_EDGES 1600000
#define D_FEAT  64
#define K_STEPS 8
#define NB_SCAN ((N_NODES + 255) / 256)   // 391 scan blocks
#define SLICE_F 8                          // floats per slice
#define SLICES  8                          // = number of XCDs
#define SLICE_ELEMS ((size_t)N_NODES * SLICE_F)

typedef unsigned long long u64;

__global__ void k_zero(int* __restrict__ p, int n) {
    int i = blockIdx.x * blockDim.x + threadIdx.x;
    if (i < n) p[i] = 0;
}

// Histogram + per-edge rank within its dst list (atomic return value).
__global__ void k_hist(const int* __restrict__ dst, int* __restrict__ counts,
                       int* __restrict__ rank, int n) {
    int i = blockIdx.x * blockDim.x + threadIdx.x;
    if (i < n) rank[i] = atomicAdd(&counts[dst[i]], 1);
}

// Phase 1: per-block sum of 256 counts
__global__ void k_bsum(const int* __restrict__ counts, int* __restrict__ blockSums, int n) {
    __shared__ int ws[4];
    int t = threadIdx.x;
    int i = blockIdx.x * 256 + t;
    int c = (i < n) ? counts[i] : 0;
    for (int off = 32; off; off >>= 1) c += __shfl_down(c, off);
    if ((t & 63) == 0) ws[t >> 6] = c;
    __syncthreads();
    if (t == 0) blockSums[blockIdx.x] = ws[0] + ws[1] + ws[2] + ws[3];
}

// Phase 2: single block scans the 391 block sums -> exclusive blockPrefix
__global__ void k_sscan(const int* __restrict__ blockSums, int* __restrict__ blockPrefix,
                        int* __restrict__ offsets, int nb, int n) {
    __shared__ int sh[512];
    int t = threadIdx.x;
    int v = (t < nb) ? blockSums[t] : 0;
    sh[t] = v;
    __syncthreads();
    for (int off = 1; off < 512; off <<= 1) {
        int u = (t >= off) ? sh[t - off] : 0;
        __syncthreads();
        sh[t] += u;
        __syncthreads();
    }
    if (t < nb) blockPrefix[t] = sh[t] - v;   // exclusive
    if (t == 511) offsets[n] = sh[511];        // total == N_EDGES
}

// Phase 3: per-block exclusive scan of counts + block prefix -> offsets
__global__ void k_bscan(const int* __restrict__ counts, const int* __restrict__ blockPrefix,
                        int* __restrict__ offsets, int n) {
    __shared__ int sh[256];
    int t = threadIdx.x;
    int i = blockIdx.x * 256 + t;
    int c = (i < n) ? counts[i] : 0;
    sh[t] = c;
    __syncthreads();
    for (int off = 1; off < 256; off <<= 1) {
        int u = (t >= off) ? sh[t - off] : 0;
        __syncthreads();
        sh[t] += u;
        __syncthreads();
    }
    int excl = sh[t] - c + blockPrefix[blockIdx.x];
    if (i < n) offsets[i] = excl;
}

// Atomic-free scatter: pos = offsets[dst] + rank. One nt 8B packed store per edge.
__global__ void k_scatter(const int* __restrict__ src, const int* __restrict__ dst,
                          const float* __restrict__ w, const int* __restrict__ offsets,
                          const int* __restrict__ rank, u64* __restrict__ csr, int n) {
    int i = blockIdx.x * blockDim.x + threadIdx.x;
    if (i < n) {
        int d = dst[i];
        int pos = offsets[d] + rank[i];
        u64 p = ((u64)__float_as_uint(w[i]) << 32) | (unsigned)src[i];
        __builtin_nontemporal_store(p, &csr[pos]);
    }
}

// x (row-major [N][64]) -> slice layout [8][N][8]. Writes fully coalesced.
__global__ void k_reshape(const float* __restrict__ x, float* __restrict__ hsl, int total) {
    int tid = blockIdx.x * blockDim.x + threadIdx.x;
    if (tid >= total) return;
    int f = tid & 7;
    int v = (tid >> 3) % N_NODES;
    int s = tid / (N_NODES * 8);
    hsl[tid] = x[(size_t)v * D_FEAT + s * 8 + f];
}

// slice layout [8][N][8] -> row-major [N][64]. Writes fully coalesced.
__global__ void k_unshape(const float* __restrict__ hsl, float* __restrict__ out, int total) {
    int tid = blockIdx.x * blockDim.x + threadIdx.x;
    if (tid >= total) return;
    int j = tid & 63;
    int v = tid >> 6;
    out[tid] = hsl[(size_t)(j >> 3) * SLICE_ELEMS + (size_t)v * SLICE_F + (j & 7)];
}

// Feature-slice propagation. slice = blockIdx & 7 -> blocks of one slice land on
// one XCD (round-robin dispatch), so gathers hit that XCD's private L2
// (slice = 3.2MB < 4MB). Wave layout: eg=lane>>3 (8 edge slots), fl=lane&7
// (8 feats); per iteration 8 edges in flight, 1 dword gather + 1 nt csr load
// per lane. xor-reduce over eg; lanes 0..7 store the 32B output slice.
__global__ __launch_bounds__(256)
void k_prop_slice(const float* __restrict__ hin, float* __restrict__ hout,
                  const int* __restrict__ offsets, const u64* __restrict__ csr, int n) {
    int slice = blockIdx.x & 7;
    int node  = (blockIdx.x >> 3) * 4 + (threadIdx.x >> 6);
    int lane  = threadIdx.x & 63;
    if (node >= n) return;
    int b = offsets[node];
    int e = offsets[node + 1];
    int eg = lane >> 3;
    int fl = lane & 7;
    const float* hs = hin + (size_t)slice * SLICE_ELEMS;
    float acc = 0.f;
    for (int i = b + eg; i < e; i += 8) {
        u64 p   = __builtin_nontemporal_load(&csr[i]);
        int s   = (int)(p & 0xffffffffu);
        float w = __uint_as_float((unsigned)(p >> 32));
        acc = fmaf(w, hs[s * SLICE_F + fl], acc);
    }
    acc += __shfl_xor(acc, 8);
    acc += __shfl_xor(acc, 16);
    acc += __shfl_xor(acc, 32);
    if (eg == 0)
        hout[(size_t)slice * SLICE_ELEMS + (size_t)node * SLICE_F + fl] = acc;
}

extern "C" void kernel_launch(void* const* d_in, const int* in_sizes, int n_in,
                              void* d_out, int out_size, void* d_ws, size_t ws_size,
                              hipStream_t stream) {
    const float* x   = (const float*)d_in[0];
    const float* ew  = (const float*)d_in[1];
    const int*   src = (const int*)d_in[2];
    const int*   dst = (const int*)d_in[3];
    float* out = (float*)d_out;

    // Workspace (~39.7 MB). rank aliases hS0: rank is consumed by k_scatter,
    // which completes before k_reshape writes hS0. d_out doubles as the
    // second slice buffer during the prop chain; k_unshape overwrites it.
    float* hS0        = (float*)d_ws;                            // N*64 floats (slice layout)
    int*   rank       = (int*)d_ws;                              // E ints (aliases hS0)
    u64*   csr        = (u64*)(hS0 + (size_t)N_NODES * D_FEAT);  // E x 8B packed (src,w)
    int*   offsets    = (int*)(csr + N_EDGES);                   // N+1 ints
    int*   counts     = offsets + (N_NODES + 1);                 // N ints
    int*   blockSums  = counts + N_NODES;                        // NB_SCAN ints
    int*   blockPref  = blockSums + NB_SCAN;                     // NB_SCAN ints

    float* hS1 = (float*)d_out;                                  // slice-layout scratch

    k_zero<<<(N_NODES + 255) / 256, 256, 0, stream>>>(counts, N_NODES);
    k_hist<<<(N_EDGES + 255) / 256, 256, 0, stream>>>(dst, counts, rank, N_EDGES);
    k_bsum<<<NB_SCAN, 256, 0, stream>>>(counts, blockSums, N_NODES);
    k_sscan<<<1, 512, 0, stream>>>(blockSums, blockPref, offsets, NB_SCAN, N_NODES);
    k_bscan<<<NB_SCAN, 256, 0, stream>>>(counts, blockPref, offsets, N_NODES);
    k_scatter<<<(N_EDGES + 255) / 256, 256, 0, stream>>>(src, dst, ew, offsets, rank,
                                                         csr, N_EDGES);

    const int total = N_NODES * D_FEAT;
    k_reshape<<<(total + 255) / 256, 256, 0, stream>>>(x, hS0, total);

    const int prop_grid = SLICES * ((N_NODES + 3) / 4);   // 200000 blocks
    for (int k = 0; k < K_STEPS; ++k) {
        const float* in = ((k & 1) == 0) ? hS0 : hS1;
        float*       o  = ((k & 1) == 0) ? hS1 : hS0;
        k_prop_slice<<<prop_grid, 256, 0, stream>>>(in, o, offsets, csr, N_NODES);
    }
    // After 8 props (even count) the result is back in hS0.
    k_unshape<<<(total + 255) / 256, 256, 0, stream>>>(hS0, out, total);
}

// Round 8
// 553.162 us; speedup vs baseline: 5.9563x; 4.3323x over previous
//
#include <hip/hip_runtime.h>

#define N_NODES 100000
#define N_EDGES 1600000
#define D_FEAT  64
#define K_STEPS 8
#define NB_SCAN ((N_NODES + 255) / 256)   // 391 scan blocks

typedef unsigned long long u64;
typedef float f4 __attribute__((ext_vector_type(4)));

__global__ void k_zero(int* __restrict__ p, int n) {
    int i = blockIdx.x * blockDim.x + threadIdx.x;
    if (i < n) p[i] = 0;
}

// Histogram + per-edge rank within its dst list (atomic return value).
__global__ void k_hist(const int* __restrict__ dst, int* __restrict__ counts,
                       int* __restrict__ rank, int n) {
    int i = blockIdx.x * blockDim.x + threadIdx.x;
    if (i < n) rank[i] = atomicAdd(&counts[dst[i]], 1);
}

// Phase 1: per-block sum of 256 counts
__global__ void k_bsum(const int* __restrict__ counts, int* __restrict__ blockSums, int n) {
    __shared__ int ws[4];
    int t = threadIdx.x;
    int i = blockIdx.x * 256 + t;
    int c = (i < n) ? counts[i] : 0;
    for (int off = 32; off; off >>= 1) c += __shfl_down(c, off);
    if ((t & 63) == 0) ws[t >> 6] = c;
    __syncthreads();
    if (t == 0) blockSums[blockIdx.x] = ws[0] + ws[1] + ws[2] + ws[3];
}

// Phase 2: single block scans the 391 block sums -> exclusive blockPrefix
__global__ void k_sscan(const int* __restrict__ blockSums, int* __restrict__ blockPrefix,
                        int* __restrict__ offsets, int nb, int n) {
    __shared__ int sh[512];
    int t = threadIdx.x;
    int v = (t < nb) ? blockSums[t] : 0;
    sh[t] = v;
    __syncthreads();
    for (int off = 1; off < 512; off <<= 1) {
        int u = (t >= off) ? sh[t - off] : 0;
        __syncthreads();
        sh[t] += u;
        __syncthreads();
    }
    if (t < nb) blockPrefix[t] = sh[t] - v;   // exclusive
    if (t == 511) offsets[n] = sh[511];        // total == N_EDGES
}

// Phase 3: per-block exclusive scan of counts + block prefix -> offsets
__global__ void k_bscan(const int* __restrict__ counts, const int* __restrict__ blockPrefix,
                        int* __restrict__ offsets, int n) {
    __shared__ int sh[256];
    int t = threadIdx.x;
    int i = blockIdx.x * 256 + t;
    int c = (i < n) ? counts[i] : 0;
    sh[t] = c;
    __syncthreads();
    for (int off = 1; off < 256; off <<= 1) {
        int u = (t >= off) ? sh[t - off] : 0;
        __syncthreads();
        sh[t] += u;
        __syncthreads();
    }
    int excl = sh[t] - c + blockPrefix[blockIdx.x];
    if (i < n) offsets[i] = excl;
}

// Atomic-free scatter: pos = offsets[dst] + rank. Plain (cached) store — csr
// is re-read by all 8 props, keep it resident.
__global__ void k_scatter(const int* __restrict__ src, const int* __restrict__ dst,
                          const float* __restrict__ w, const int* __restrict__ offsets,
                          const int* __restrict__ rank, u64* __restrict__ csr, int n) {
    int i = blockIdx.x * blockDim.x + threadIdx.x;
    if (i < n) {
        int d = dst[i];
        int pos = offsets[d] + rank[i];
        csr[pos] = ((u64)__float_as_uint(w[i]) << 32) | (unsigned)src[i];
    }
}

// One wave per node. lane = (edge_slot eg=lane>>3 [8 slots], fl=lane&7).
// 2-way unrolled: 16 edges in flight per iteration (4 f4 gathers + 2 csr
// loads outstanding per lane). OOB slot is predicated to (row 0, w=0) —
// row 0 is cache-hot, w=0 keeps the sum exact. All loads/stores cached:
// h and csr stay L2/LLC-resident across the 8 props.
__global__ __launch_bounds__(256)
void k_prop(const float* __restrict__ hin, float* __restrict__ hout,
            const int* __restrict__ offsets, const u64* __restrict__ csr, int n) {
    int wave = (blockIdx.x * blockDim.x + threadIdx.x) >> 6;
    int lane = threadIdx.x & 63;
    if (wave >= n) return;
    int b = offsets[wave];
    int e = offsets[wave + 1];
    int eg = lane >> 3;        // edge slot 0..7
    int fl = lane & 7;         // feature group (8 floats)
    f4 a0 = {0.f, 0.f, 0.f, 0.f};
    f4 a1 = {0.f, 0.f, 0.f, 0.f};
    f4 c0 = {0.f, 0.f, 0.f, 0.f};
    f4 c1 = {0.f, 0.f, 0.f, 0.f};
    for (int i = b + eg; i < e; i += 16) {
        int  iB  = i + 8;
        bool okB = iB < e;
        u64 pA = csr[i];
        u64 pB = okB ? csr[iB] : 0;
        int   sA = (int)(pA & 0xffffffffu);
        float wA = __uint_as_float((unsigned)(pA >> 32));
        int   sB = okB ? (int)(pB & 0xffffffffu) : 0;
        float wB = okB ? __uint_as_float((unsigned)(pB >> 32)) : 0.f;
        const f4* rA = reinterpret_cast<const f4*>(&hin[((size_t)sA << 6) + (fl << 3)]);
        const f4* rB = reinterpret_cast<const f4*>(&hin[((size_t)sB << 6) + (fl << 3)]);
        f4 vA0 = rA[0], vA1 = rA[1];
        f4 vB0 = rB[0], vB1 = rB[1];
        a0.x = fmaf(wA, vA0.x, a0.x); a0.y = fmaf(wA, vA0.y, a0.y);
        a0.z = fmaf(wA, vA0.z, a0.z); a0.w = fmaf(wA, vA0.w, a0.w);
        a1.x = fmaf(wA, vA1.x, a1.x); a1.y = fmaf(wA, vA1.y, a1.y);
        a1.z = fmaf(wA, vA1.z, a1.z); a1.w = fmaf(wA, vA1.w, a1.w);
        c0.x = fmaf(wB, vB0.x, c0.x); c0.y = fmaf(wB, vB0.y, c0.y);
        c0.z = fmaf(wB, vB0.z, c0.z); c0.w = fmaf(wB, vB0.w, c0.w);
        c1.x = fmaf(wB, vB1.x, c1.x); c1.y = fmaf(wB, vB1.y, c1.y);
        c1.z = fmaf(wB, vB1.z, c1.z); c1.w = fmaf(wB, vB1.w, c1.w);
    }
    a0.x += c0.x; a0.y += c0.y; a0.z += c0.z; a0.w += c0.w;
    a1.x += c1.x; a1.y += c1.y; a1.z += c1.z; a1.w += c1.w;
    #pragma unroll
    for (int off = 8; off < 64; off <<= 1) {
        a0.x += __shfl_xor(a0.x, off);
        a0.y += __shfl_xor(a0.y, off);
        a0.z += __shfl_xor(a0.z, off);
        a0.w += __shfl_xor(a0.w, off);
        a1.x += __shfl_xor(a1.x, off);
        a1.y += __shfl_xor(a1.y, off);
        a1.z += __shfl_xor(a1.z, off);
        a1.w += __shfl_xor(a1.w, off);
    }
    if (eg == 0) {
        f4* o = reinterpret_cast<f4*>(&hout[((size_t)wave << 6) + (fl << 3)]);
        o[0] = a0;
        o[1] = a1;
    }
}

extern "C" void kernel_launch(void* const* d_in, const int* in_sizes, int n_in,
                              void* d_out, int out_size, void* d_ws, size_t ws_size,
                              hipStream_t stream) {
    const float* x   = (const float*)d_in[0];
    const float* ew  = (const float*)d_in[1];
    const int*   src = (const int*)d_in[2];
    const int*   dst = (const int*)d_in[3];
    float* out = (float*)d_out;

    // Workspace (~39.7 MB). rank aliases hA: rank is consumed by k_scatter,
    // which completes before the first k_prop writes hA. Prop chain
    // ping-pongs hA <-> d_out; k=7 (odd) lands in d_out.
    float* hA         = (float*)d_ws;                           // N*D floats
    int*   rank       = (int*)d_ws;                             // E ints (aliases hA)
    u64*   csr        = (u64*)(hA + (size_t)N_NODES * D_FEAT);  // E x 8B packed (src,w)
    int*   offsets    = (int*)(csr + N_EDGES);                  // N+1 ints
    int*   counts     = offsets + (N_NODES + 1);                // N ints
    int*   blockSums  = counts + N_NODES;                       // NB_SCAN ints
    int*   blockPref  = blockSums + NB_SCAN;                    // NB_SCAN ints

    k_zero<<<(N_NODES + 255) / 256, 256, 0, stream>>>(counts, N_NODES);
    k_hist<<<(N_EDGES + 255) / 256, 256, 0, stream>>>(dst, counts, rank, N_EDGES);
    k_bsum<<<NB_SCAN, 256, 0, stream>>>(counts, blockSums, N_NODES);
    k_sscan<<<1, 512, 0, stream>>>(blockSums, blockPref, offsets, NB_SCAN, N_NODES);
    k_bscan<<<NB_SCAN, 256, 0, stream>>>(counts, blockPref, offsets, N_NODES);
    k_scatter<<<(N_EDGES + 255) / 256, 256, 0, stream>>>(src, dst, ew, offsets, rank,
                                                         csr, N_EDGES);

    const int prop_grid = (N_NODES * 64 + 255) / 256;
    const float* in = x;
    for (int k = 0; k < K_STEPS; ++k) {
        float* o = (k & 1) ? out : hA;    // k=7 (last, odd) writes d_out
        k_prop<<<prop_grid, 256, 0, stream>>>(in, o, offsets, csr, N_NODES);
        in = o;
    }
}

// Round 9
// 549.259 us; speedup vs baseline: 5.9986x; 1.0071x over previous
//
#include <hip/hip_runtime.h>

#define N_NODES 100000
#define N_EDGES 1600000
#define D_FEAT  64
#define K_STEPS 8
#define NB_SCAN ((N_NODES + 255) / 256)   // 391 scan blocks

typedef unsigned long long u64;
typedef float f4 __attribute__((ext_vector_type(4)));

__global__ void k_zero(int* __restrict__ p, int n) {
    int i = blockIdx.x * blockDim.x + threadIdx.x;
    if (i < n) p[i] = 0;
}

// Histogram + per-edge rank. 4 edges/thread: 4 independent returning atomics
// in flight per thread (latency-bound kernel -> 4x MLP).
__global__ void k_hist(const int* __restrict__ dst, int* __restrict__ counts,
                       int* __restrict__ rank, int n) {
    int base = (blockIdx.x * blockDim.x + threadIdx.x) * 4;
    if (base >= n) return;
    int4 d = *reinterpret_cast<const int4*>(&dst[base]);
    int r0 = atomicAdd(&counts[d.x], 1);
    int r1 = atomicAdd(&counts[d.y], 1);
    int r2 = atomicAdd(&counts[d.z], 1);
    int r3 = atomicAdd(&counts[d.w], 1);
    *reinterpret_cast<int4*>(&rank[base]) = make_int4(r0, r1, r2, r3);
}

// Phase 1: per-block sum of 256 counts
__global__ void k_bsum(const int* __restrict__ counts, int* __restrict__ blockSums, int n) {
    __shared__ int ws[4];
    int t = threadIdx.x;
    int i = blockIdx.x * 256 + t;
    int c = (i < n) ? counts[i] : 0;
    for (int off = 32; off; off >>= 1) c += __shfl_down(c, off);
    if ((t & 63) == 0) ws[t >> 6] = c;
    __syncthreads();
    if (t == 0) blockSums[blockIdx.x] = ws[0] + ws[1] + ws[2] + ws[3];
}

// Phase 2: single block scans the 391 block sums -> exclusive blockPrefix
__global__ void k_sscan(const int* __restrict__ blockSums, int* __restrict__ blockPrefix,
                        int* __restrict__ offsets, int nb, int n) {
    __shared__ int sh[512];
    int t = threadIdx.x;
    int v = (t < nb) ? blockSums[t] : 0;
    sh[t] = v;
    __syncthreads();
    for (int off = 1; off < 512; off <<= 1) {
        int u = (t >= off) ? sh[t - off] : 0;
        __syncthreads();
        sh[t] += u;
        __syncthreads();
    }
    if (t < nb) blockPrefix[t] = sh[t] - v;   // exclusive
    if (t == 511) offsets[n] = sh[511];        // total == N_EDGES
}

// Phase 3: per-block exclusive scan of counts + block prefix -> offsets
__global__ void k_bscan(const int* __restrict__ counts, const int* __restrict__ blockPrefix,
                        int* __restrict__ offsets, int n) {
    __shared__ int sh[256];
    int t = threadIdx.x;
    int i = blockIdx.x * 256 + t;
    int c = (i < n) ? counts[i] : 0;
    sh[t] = c;
    __syncthreads();
    for (int off = 1; off < 256; off <<= 1) {
        int u = (t >= off) ? sh[t - off] : 0;
        __syncthreads();
        sh[t] += u;
        __syncthreads();
    }
    int excl = sh[t] - c + blockPrefix[blockIdx.x];
    if (i < n) offsets[i] = excl;
}

// Atomic-free scatter, 4 edges/thread: 4 independent random offset reads and
// 4 independent 8B packed stores in flight. Cached stores keep csr LLC-hot.
__global__ void k_scatter(const int* __restrict__ src, const int* __restrict__ dst,
                          const float* __restrict__ w, const int* __restrict__ offsets,
                          const int* __restrict__ rank, u64* __restrict__ csr, int n) {
    int base = (blockIdx.x * blockDim.x + threadIdx.x) * 4;
    if (base >= n) return;
    int4   s = *reinterpret_cast<const int4*>(&src[base]);
    int4   d = *reinterpret_cast<const int4*>(&dst[base]);
    float4 v = *reinterpret_cast<const float4*>(&w[base]);
    int4   r = *reinterpret_cast<const int4*>(&rank[base]);
    int p0 = offsets[d.x] + r.x;
    int p1 = offsets[d.y] + r.y;
    int p2 = offsets[d.z] + r.z;
    int p3 = offsets[d.w] + r.w;
    csr[p0] = ((u64)__float_as_uint(v.x) << 32) | (unsigned)s.x;
    csr[p1] = ((u64)__float_as_uint(v.y) << 32) | (unsigned)s.y;
    csr[p2] = ((u64)__float_as_uint(v.z) << 32) | (unsigned)s.z;
    csr[p3] = ((u64)__float_as_uint(v.w) << 32) | (unsigned)s.w;
}

// One wave per node. lane = (edge_slot eg=lane>>3 [8 slots], fl=lane&7).
// 2-way unrolled: 16 edges in flight per iteration. OOB slot predicated to
// (row 0, w=0). All accesses cached: h + csr stay L2/LLC-resident.
__global__ __launch_bounds__(256)
void k_prop(const float* __restrict__ hin, float* __restrict__ hout,
            const int* __restrict__ offsets, const u64* __restrict__ csr, int n) {
    int wave = (blockIdx.x * blockDim.x + threadIdx.x) >> 6;
    int lane = threadIdx.x & 63;
    if (wave >= n) return;
    int b = offsets[wave];
    int e = offsets[wave + 1];
    int eg = lane >> 3;        // edge slot 0..7
    int fl = lane & 7;         // feature group (8 floats)
    f4 a0 = {0.f, 0.f, 0.f, 0.f};
    f4 a1 = {0.f, 0.f, 0.f, 0.f};
    f4 c0 = {0.f, 0.f, 0.f, 0.f};
    f4 c1 = {0.f, 0.f, 0.f, 0.f};
    for (int i = b + eg; i < e; i += 16) {
        int  iB  = i + 8;
        bool okB = iB < e;
        u64 pA = csr[i];
        u64 pB = okB ? csr[iB] : 0;
        int   sA = (int)(pA & 0xffffffffu);
        float wA = __uint_as_float((unsigned)(pA >> 32));
        int   sB = okB ? (int)(pB & 0xffffffffu) : 0;
        float wB = okB ? __uint_as_float((unsigned)(pB >> 32)) : 0.f;
        const f4* rA = reinterpret_cast<const f4*>(&hin[((size_t)sA << 6) + (fl << 3)]);
        const f4* rB = reinterpret_cast<const f4*>(&hin[((size_t)sB << 6) + (fl << 3)]);
        f4 vA0 = rA[0], vA1 = rA[1];
        f4 vB0 = rB[0], vB1 = rB[1];
        a0.x = fmaf(wA, vA0.x, a0.x); a0.y = fmaf(wA, vA0.y, a0.y);
        a0.z = fmaf(wA, vA0.z, a0.z); a0.w = fmaf(wA, vA0.w, a0.w);
        a1.x = fmaf(wA, vA1.x, a1.x); a1.y = fmaf(wA, vA1.y, a1.y);
        a1.z = fmaf(wA, vA1.z, a1.z); a1.w = fmaf(wA, vA1.w, a1.w);
        c0.x = fmaf(wB, vB0.x, c0.x); c0.y = fmaf(wB, vB0.y, c0.y);
        c0.z = fmaf(wB, vB0.z, c0.z); c0.w = fmaf(wB, vB0.w, c0.w);
        c1.x = fmaf(wB, vB1.x, c1.x); c1.y = fmaf(wB, vB1.y, c1.y);
        c1.z = fmaf(wB, vB1.z, c1.z); c1.w = fmaf(wB, vB1.w, c1.w);
    }
    a0.x += c0.x; a0.y += c0.y; a0.z += c0.z; a0.w += c0.w;
    a1.x += c1.x; a1.y += c1.y; a1.z += c1.z; a1.w += c1.w;
    #pragma unroll
    for (int off = 8; off < 64; off <<= 1) {
        a0.x += __shfl_xor(a0.x, off);
        a0.y += __shfl_xor(a0.y, off);
        a0.z += __shfl_xor(a0.z, off);
        a0.w += __shfl_xor(a0.w, off);
        a1.x += __shfl_xor(a1.x, off);
        a1.y += __shfl_xor(a1.y, off);
        a1.z += __shfl_xor(a1.z, off);
        a1.w += __shfl_xor(a1.w, off);
    }
    if (eg == 0) {
        f4* o = reinterpret_cast<f4*>(&hout[((size_t)wave << 6) + (fl << 3)]);
        o[0] = a0;
        o[1] = a1;
    }
}

extern "C" void kernel_launch(void* const* d_in, const int* in_sizes, int n_in,
                              void* d_out, int out_size, void* d_ws, size_t ws_size,
                              hipStream_t stream) {
    const float* x   = (const float*)d_in[0];
    const float* ew  = (const float*)d_in[1];
    const int*   src = (const int*)d_in[2];
    const int*   dst = (const int*)d_in[3];
    float* out = (float*)d_out;

    // Workspace (~39.7 MB). rank aliases hA: rank is consumed by k_scatter,
    // which completes before the first k_prop writes hA. Prop chain
    // ping-pongs hA <-> d_out; k=7 (odd) lands in d_out.
    float* hA         = (float*)d_ws;                           // N*D floats
    int*   rank       = (int*)d_ws;                             // E ints (aliases hA)
    u64*   csr        = (u64*)(hA + (size_t)N_NODES * D_FEAT);  // E x 8B packed (src,w)
    int*   offsets    = (int*)(csr + N_EDGES);                  // N+1 ints
    int*   counts     = offsets + (N_NODES + 1);                // N ints
    int*   blockSums  = counts + N_NODES;                       // NB_SCAN ints
    int*   blockPref  = blockSums + NB_SCAN;                    // NB_SCAN ints

    k_zero<<<(N_NODES + 255) / 256, 256, 0, stream>>>(counts, N_NODES);
    k_hist<<<(N_EDGES / 4 + 255) / 256, 256, 0, stream>>>(dst, counts, rank, N_EDGES);
    k_bsum<<<NB_SCAN, 256, 0, stream>>>(counts, blockSums, N_NODES);
    k_sscan<<<1, 512, 0, stream>>>(blockSums, blockPref, offsets, NB_SCAN, N_NODES);
    k_bscan<<<NB_SCAN, 256, 0, stream>>>(counts, blockPref, offsets, N_NODES);
    k_scatter<<<(N_EDGES / 4 + 255) / 256, 256, 0, stream>>>(src, dst, ew, offsets, rank,
                                                             csr, N_EDGES);

    const int prop_grid = (N_NODES * 64 + 255) / 256;
    const float* in = x;
    for (int k = 0; k < K_STEPS; ++k) {
        float* o = (k & 1) ? out : hA;    // k=7 (last, odd) writes d_out
        k_prop<<<prop_grid, 256, 0, stream>>>(in, o, offsets, csr, N_NODES);
        in = o;
    }
}